// Round 10
// baseline (127.443 us; speedup 1.0000x reference)
//
#include <hip/hip_runtime.h>

typedef unsigned short u16;
typedef __bf16 bf16x8 __attribute__((ext_vector_type(8)));
typedef float f32x4 __attribute__((ext_vector_type(4)));

struct alignas(16) V4 { unsigned x, y, z, w; };

#if __has_builtin(__builtin_amdgcn_exp2f)
#define EXP2(x) __builtin_amdgcn_exp2f(x)
#else
#define EXP2(x) __expf((x) * 0.6931471805599453f)
#endif
#define L2E 1.4426950408889634f

// f32 -> bf16 RTNE (bit-twiddle; HW-verified R1/R4)
__device__ __forceinline__ u16 f2b(float f) {
  unsigned u = __builtin_bit_cast(unsigned, f);
  u += 0x7FFFu + ((u >> 16) & 1u);
  return (u16)(u >> 16);
}
// RTNE pack of two f32 -> u32 (lo = a, hi = b)
__device__ __forceinline__ unsigned pk2(float a, float b) {
  return (unsigned)f2b(a) | ((unsigned)f2b(b) << 16);
}
// HW packed cvt: used ONLY for P fragment (validated R8/R9: absmax unchanged)
__device__ __forceinline__ unsigned pkbf(float a, float b) {
  unsigned d;
  asm("v_cvt_pk_bf16_f32 %0, %1, %2" : "=v"(d) : "v"(a), "v"(b));
  return d;
}
__device__ __forceinline__ bf16x8 asb(V4 v) { return __builtin_bit_cast(bf16x8, v); }
__device__ __forceinline__ bf16x8 mk8(unsigned a, unsigned b, unsigned c, unsigned d) {
  V4 v; v.x = a; v.y = b; v.z = c; v.w = d; return asb(v);
}
__device__ __forceinline__ V4 ldg16(const u16* p) { return *reinterpret_cast<const V4*>(p); }
__device__ __forceinline__ f32x4 mfma16(bf16x8 a, bf16x8 b, f32x4 c) {
  return __builtin_amdgcn_mfma_f32_16x16x32_bf16(a, b, c, 0, 0, 0);
}
// Direct global->LDS DMA, 16B/lane, LDS dest = wave-uniform base + lane*16.
__device__ __forceinline__ void gload_lds16(const void* g, void* l) {
  __builtin_amdgcn_global_load_lds(
      (const __attribute__((address_space(1))) int*)g,
      (__attribute__((address_space(3))) int*)l, 16, 0, 0);
}

// ---------------------------------------------------------------------------
// Prep: transpose+cast weights to bf16, cast descriptor to bf16.
// ---------------------------------------------------------------------------
__global__ __launch_bounds__(256) void k_prep(
    const float* __restrict__ wq, const float* __restrict__ wk,
    const float* __restrict__ wv, const float* __restrict__ wd,
    const float* __restrict__ wo, const float* __restrict__ desc,
    u16* __restrict__ wqT, u16* __restrict__ wkT, u16* __restrict__ wvT,
    u16* __restrict__ wdT, u16* __restrict__ woT, u16* __restrict__ descb) {
  int i = blockIdx.x * 256 + threadIdx.x;
  if (i < 32768) {                                   // wqT[n][d] = wq[d][n]
    int n = i >> 6, d = i & 63;
    wqT[i] = f2b(wq[d * 512 + n]);
  } else if (i < 65536) {
    int j = i - 32768; int n = j >> 6, d = j & 63;
    wkT[j] = f2b(wk[d * 512 + n]);
  } else if (i < 98304) {
    int j = i - 65536; int n = j >> 6, d = j & 63;
    wvT[j] = f2b(wv[d * 512 + n]);
  } else if (i < 114688) {                           // wdT[e][v] = wd[v][e]
    int j = i - 98304; int e = j >> 8, v = j & 255;
    wdT[j] = f2b(wd[v * 64 + e]);
  } else if (i < 147456) {                           // woT[n][k] = wo[k][n]
    int j = i - 114688; int n = j >> 9, kk = j & 511;
    woT[j] = f2b(wo[kk * 64 + n]);
  } else if (i < 409600) {                           // descb, 4 elems/thread
    int j = (i - 147456) * 4;
    const f32x4 dv = *reinterpret_cast<const f32x4*>(desc + j);
    uint2 pw; pw.x = pk2(dv[0], dv[1]); pw.y = pk2(dv[2], dv[3]);
    *reinterpret_cast<uint2*>(descb + j) = pw;
  }
}

// ---------------------------------------------------------------------------
// Conv3d(P=4,stride=4) + LayerNorm + pos_emb -> vox_emb bf16 [16384][64]
// R10: pl is wave-local -> no per-iteration barriers (only one after wT fill).
// ---------------------------------------------------------------------------
__global__ __launch_bounds__(256) void k_convln(
    const float* __restrict__ vox, const float* __restrict__ cw,
    const float* __restrict__ cb, const float* __restrict__ lng,
    const float* __restrict__ lnb, const float* __restrict__ pos,
    u16* __restrict__ vox_emb) {
  __shared__ float wT[64 * 65];
  __shared__ float pl[4][64];
  const int t = threadIdx.x;
  for (int i = t; i < 4096; i += 256) wT[(i & 63) * 65 + (i >> 6)] = cw[i];
  __syncthreads();
  const int w = t >> 6, lane = t & 63;
  const float cbl = cb[lane], lg = lng[lane], lb = lnb[lane];
  const int i3 = lane >> 4, j3 = (lane >> 2) & 3, k3 = lane & 3;
  for (int i = 0; i < 8; ++i) {
    const int row = blockIdx.x * 32 + w * 8 + i;
    const int b = row >> 12, np = row & 4095;
    const int pd = np >> 8, ph = (np >> 4) & 15, pw = np & 15;
    pl[w][lane] = vox[(size_t)b * 262144 + (size_t)(pd * 4 + i3) * 4096 +
                      (ph * 4 + j3) * 64 + (pw * 4 + k3)];
    float acc = cbl;
    #pragma unroll
    for (int v = 0; v < 64; ++v) acc += pl[w][v] * wT[v * 65 + lane];
    float s1 = acc, s2 = acc * acc;
    #pragma unroll
    for (int m = 1; m < 64; m <<= 1) { s1 += __shfl_xor(s1, m); s2 += __shfl_xor(s2, m); }
    const float mu = s1 * (1.0f / 64.0f);
    const float var = s2 * (1.0f / 64.0f) - mu * mu;
    const float y = (acc - mu) * rsqrtf(var + 1e-5f) * lg + lb + pos[np * 64 + lane];
    vox_emb[(size_t)row * 64 + lane] = f2b(y);
  }
}

// ---------------------------------------------------------------------------
// des_emb = descb[4096][256] @ wd + bd -> bf16 [4096][64]
// R10: et split across blockIdx.y (4x wave count).
// ---------------------------------------------------------------------------
__global__ __launch_bounds__(64) void k_des(
    const u16* __restrict__ descb, const u16* __restrict__ wdT,
    const float* __restrict__ bd, u16* __restrict__ desemb) {
  const int lane = threadIdx.x, lr = lane & 15, lc = lane >> 4;
  const int sd0 = blockIdx.x * 16, et = blockIdx.y;
  f32x4 acc = {0.f, 0.f, 0.f, 0.f};
  #pragma unroll
  for (int kc = 0; kc < 8; ++kc) {
    const bf16x8 db = asb(ldg16(descb + (size_t)(sd0 + lr) * 256 + kc * 32 + lc * 8));
    const bf16x8 wa = asb(ldg16(wdT + (size_t)(et * 16 + lr) * 256 + kc * 32 + lc * 8));
    acc = mfma16(wa, db, acc);
  }
  const f32x4 bdv = *reinterpret_cast<const f32x4*>(bd + et * 16 + lc * 4);
  uint2 pw;
  pw.x = pk2(acc[0] + bdv[0], acc[1] + bdv[1]);
  pw.y = pk2(acc[2] + bdv[2], acc[3] + bdv[3]);
  *reinterpret_cast<uint2*>(desemb + (size_t)(sd0 + lr) * 64 + et * 16 + lc * 4) = pw;
}

// ---------------------------------------------------------------------------
// K/V projections. Images per (bh, 64-row tile): K 8KB (row sd: 128B,
// col16 ^= sd&7), V 8KB (row e: 128B, col16 ^= e&7). kb bytes identical to
// R9 (128*sd linear); vtb re-tiled to 64-k tiles. ekl = -|k|^2/2 f32.
// R10: h split across blockIdx.y (4x wave count).
// ---------------------------------------------------------------------------
__global__ __launch_bounds__(64) void k_kvproj(
    const u16* __restrict__ desemb, const u16* __restrict__ wkT,
    const float* __restrict__ bk, const u16* __restrict__ wvT,
    const float* __restrict__ bv, u16* __restrict__ kb,
    float* __restrict__ ekl, u16* __restrict__ vtb) {
  const int lane = threadIdx.x, lr = lane & 15, lc = lane >> 4;
  const int x = blockIdx.x, h = blockIdx.y;
  const int b = x >> 6, sb = x & 63, sd0 = sb * 16;
  char* kbc = reinterpret_cast<char*>(kb);
  char* vtc = reinterpret_cast<char*>(vtb);
  const u16* drow = desemb + (size_t)(x * 16 + lr) * 64;
  const bf16x8 da0 = asb(ldg16(drow + lc * 8));
  const bf16x8 da1 = asb(ldg16(drow + 32 + lc * 8));
  const int sd = sd0 + lr, ktK = sd >> 6, rK = sd & 63, xrK = sd & 7;
  float sq = 0.f;
  #pragma unroll
  for (int et = 0; et < 4; ++et) {                  // K pass (flipped)
    const int etg = h * 4 + et;
    const u16* wrow = wkT + (size_t)(etg * 16 + lr) * 64;
    f32x4 acc = {0.f, 0.f, 0.f, 0.f};
    acc = mfma16(asb(ldg16(wrow + lc * 8)), da0, acc);
    acc = mfma16(asb(ldg16(wrow + 32 + lc * 8)), da1, acc);
    const f32x4 bkv = *reinterpret_cast<const f32x4*>(bk + etg * 16 + lc * 4);
    const float k0 = acc[0] + bkv[0], k1 = acc[1] + bkv[1];
    const float k2 = acc[2] + bkv[2], k3 = acc[3] + bkv[3];
    sq += k0 * k0 + k1 * k1 + k2 * k2 + k3 * k3;
    const int col16s = (((et >> 1) * 4 + lc) ^ xrK);
    uint2 pw; pw.x = pk2(k0, k1); pw.y = pk2(k2, k3);
    *reinterpret_cast<uint2*>(kbc + (size_t)(b * 8 + h) * 131072 + ktK * 8192 +
                              rK * 128 + col16s * 16 + (et & 1) * 8) = pw;
  }
  {
    float s = sq;
    s += __shfl_xor(s, 16); s += __shfl_xor(s, 32);
    if (lc == 0) ekl[(size_t)(b * 8 + h) * 1024 + sd0 + lr] = -0.5f * s;
  }
  const int ktV = sb >> 2, kkl2 = (sb >> 1) & 1, half8 = sb & 1;
  #pragma unroll
  for (int et = 0; et < 4; ++et) {                  // V pass
    const int etg = h * 4 + et;
    const u16* wrow = wvT + (size_t)(etg * 16 + lr) * 64;
    f32x4 acc = {0.f, 0.f, 0.f, 0.f};
    acc = mfma16(da0, asb(ldg16(wrow + lc * 8)), acc);
    acc = mfma16(da1, asb(ldg16(wrow + 32 + lc * 8)), acc);
    const float bvs = bv[etg * 16 + lr];
    const int e = et * 16 + lr;
    const int col16s = ((kkl2 * 4 + lc) ^ (e & 7));
    uint2 pw;
    pw.x = pk2(acc[0] + bvs, acc[1] + bvs);
    pw.y = pk2(acc[2] + bvs, acc[3] + bvs);
    *reinterpret_cast<uint2*>(vtc + (size_t)(b * 8 + h) * 131072 + ktV * 8192 +
                              e * 128 + col16s * 16 + half8 * 8) = pw;
  }
}

// ---------------------------------------------------------------------------
// Fused Q-projection + L2 attention. R9-validated arithmetic (frozen).
// R10: 16 tiles of 64 k-rows, double-buffered LDS; stage t+1 issued BEFORE
// computing tile t (single __syncthreads per tile drains an already-covered
// vmcnt); ekl staged into LDS (no in-loop global loads).
// ---------------------------------------------------------------------------
__global__ __launch_bounds__(256, 4) void k_attn(
    const u16* __restrict__ vox_emb, const u16* __restrict__ wqT,
    const float* __restrict__ bq, const float* __restrict__ alpha,
    const u16* __restrict__ kb, const float* __restrict__ eklg,
    const u16* __restrict__ vtb, u16* __restrict__ attn) {
  __shared__ __align__(16) char Kb[2][8192];   // 64 rows x 128B per buffer
  __shared__ __align__(16) char Vb[2][8192];   // 64 e-rows x 128B per buffer
  __shared__ __align__(16) float El[2][64];    // -|k|^2/2 per buffer
  const int t = threadIdx.x, w = t >> 6, lane = t & 63, lr = lane & 15, lc = lane >> 4;
  const int bh = blockIdx.y, b = bh >> 3, h = bh & 7;
  const int q0 = blockIdx.x * 128 + w * 32;   // this wave's 32 q rows

  // ---- Q: q = vox_emb @ wq + bq; fragments hold f2b(q) (unscaled, frozen)
  bf16x8 qf0[2], qf1[2];
  float avL[2];
  {
    bf16x8 vb0[2], vb1[2];
    #pragma unroll
    for (int g = 0; g < 2; ++g) {
      const u16* vrow = vox_emb + (size_t)(b * 4096 + q0 + g * 16 + lr) * 64;
      vb0[g] = asb(ldg16(vrow + lc * 8));
      vb1[g] = asb(ldg16(vrow + 32 + lc * 8));
    }
    float sq[2] = {0.f, 0.f};
    unsigned qd[2][4][2];
    #pragma unroll
    for (int et = 0; et < 4; ++et) {
      const u16* wrow = wqT + (size_t)((h * 4 + et) * 16 + lr) * 64;
      const bf16x8 wa0 = asb(ldg16(wrow + lc * 8));
      const bf16x8 wa1 = asb(ldg16(wrow + 32 + lc * 8));
      const f32x4 bqv = *reinterpret_cast<const f32x4*>(bq + (h * 4 + et) * 16 + lc * 4);
      #pragma unroll
      for (int g = 0; g < 2; ++g) {
        f32x4 acc = {0.f, 0.f, 0.f, 0.f};
        acc = mfma16(wa0, vb0[g], acc);
        acc = mfma16(wa1, vb1[g], acc);
        const float v0 = acc[0] + bqv[0], v1 = acc[1] + bqv[1];
        const float v2 = acc[2] + bqv[2], v3 = acc[3] + bqv[3];
        sq[g] += v0 * v0 + v1 * v1 + v2 * v2 + v3 * v3;
        qd[g][et][0] = pk2(v0, v1);
        qd[g][et][1] = pk2(v2, v3);
      }
    }
    const float ca = L2E * 0.125f * alpha[0];
    #pragma unroll
    for (int g = 0; g < 2; ++g) {
      float s = sq[g];
      s += __shfl_xor(s, 16); s += __shfl_xor(s, 32);
      avL[g] = ca * __expf(-s);     // log2e * alpha*SCALE*exp(-|q|^2)
      qf0[g] = mk8(qd[g][0][0], qd[g][0][1], qd[g][1][0], qd[g][1][1]);
      qf1[g] = mk8(qd[g][2][0], qd[g][2][1], qd[g][3][0], qd[g][3][1]);
    }
  }

  const f32x4 z = {0.f, 0.f, 0.f, 0.f};
  f32x4 o[2][4];
  float dn[2] = {0.f, 0.f};
  #pragma unroll
  for (int g = 0; g < 2; ++g)
    #pragma unroll
    for (int m = 0; m < 4; ++m) o[g][m] = z;

  const char* kimg = reinterpret_cast<const char*>(kb) + (size_t)bh * 131072;
  const char* vimg = reinterpret_cast<const char*>(vtb) + (size_t)bh * 131072;
  const float* ekh = eklg + (size_t)bh * 1024;
  const int xr = lr & 7;
  const float C2 = 2.8853900817779268f;        // 2*log2(e)

  auto stage = [&](int tt, int pb) {
    const char* kg = kimg + (size_t)tt * 8192 + w * 2048 + lane * 16;
    const char* vg = vimg + (size_t)tt * 8192 + w * 2048 + lane * 16;
    char* kl = Kb[pb] + w * 2048;
    char* vl = Vb[pb] + w * 2048;
    gload_lds16(kg, kl); gload_lds16(kg + 1024, kl + 1024);
    gload_lds16(vg, vl); gload_lds16(vg + 1024, vl + 1024);
    if (w == 0 && lane < 16)
      gload_lds16(reinterpret_cast<const char*>(ekh + tt * 64) + lane * 16,
                  reinterpret_cast<char*>(El[pb]));
  };
  auto compute = [&](const char* Kt, const char* Vt, const float* Et) {
    #pragma unroll
    for (int c2 = 0; c2 < 2; ++c2) {
      const char* kr0 = Kt + (c2 * 32 + lr) * 128;
      const char* kr1 = kr0 + 2048;
      const bf16x8 ka00 = asb(*reinterpret_cast<const V4*>(kr0 + ((lc ^ xr) << 4)));
      const bf16x8 ka01 = asb(*reinterpret_cast<const V4*>(kr0 + (((lc + 4) ^ xr) << 4)));
      const bf16x8 ka10 = asb(*reinterpret_cast<const V4*>(kr1 + ((lc ^ xr) << 4)));
      const bf16x8 ka11 = asb(*reinterpret_cast<const V4*>(kr1 + (((lc + 4) ^ xr) << 4)));
      const int vcol = ((c2 * 4 + lc) ^ xr) << 4;
      const char* vrb = Vt + lr * 128 + vcol;
      const bf16x8 va0 = asb(*reinterpret_cast<const V4*>(vrb));
      const bf16x8 va1 = asb(*reinterpret_cast<const V4*>(vrb + 2048));
      const bf16x8 va2 = asb(*reinterpret_cast<const V4*>(vrb + 4096));
      const bf16x8 va3 = asb(*reinterpret_cast<const V4*>(vrb + 6144));
      const f32x4 ce0 = *reinterpret_cast<const f32x4*>(Et + c2 * 32 + lc * 4);
      const f32x4 ce1 = *reinterpret_cast<const f32x4*>(Et + c2 * 32 + 16 + lc * 4);
      #pragma unroll
      for (int g = 0; g < 2; ++g) {
        f32x4 s0 = ce0, s1 = ce1;   // C-init = -|k|^2/2
        s0 = mfma16(ka00, qf0[g], s0); s0 = mfma16(ka01, qf1[g], s0);
        s1 = mfma16(ka10, qf0[g], s1); s1 = mfma16(ka11, qf1[g], s1);
        const float t00 = EXP2(C2 * s0[0]), t01 = EXP2(C2 * s0[1]);
        const float t02 = EXP2(C2 * s0[2]), t03 = EXP2(C2 * s0[3]);
        const float t10 = EXP2(C2 * s1[0]), t11 = EXP2(C2 * s1[1]);
        const float t12 = EXP2(C2 * s1[2]), t13 = EXP2(C2 * s1[3]);
        const float p00 = EXP2(avL[g] * t00), p01 = EXP2(avL[g] * t01);
        const float p02 = EXP2(avL[g] * t02), p03 = EXP2(avL[g] * t03);
        const float p10 = EXP2(avL[g] * t10), p11 = EXP2(avL[g] * t11);
        const float p12 = EXP2(avL[g] * t12), p13 = EXP2(avL[g] * t13);
        dn[g] += ((p00 + p01) + (p02 + p03)) + ((p10 + p11) + (p12 + p13));
        const bf16x8 pf = mk8(pkbf(p00, p01), pkbf(p02, p03),
                              pkbf(p10, p11), pkbf(p12, p13));
        o[g][0] = mfma16(va0, pf, o[g][0]);
        o[g][1] = mfma16(va1, pf, o[g][1]);
        o[g][2] = mfma16(va2, pf, o[g][2]);
        o[g][3] = mfma16(va3, pf, o[g][3]);
      }
    }
  };

  stage(0, 0);
  __syncthreads();
  for (int tt = 0; tt < 8; ++tt) {
    stage(tt * 2 + 1, 1);                     // prefetch odd tile
    __builtin_amdgcn_sched_barrier(0);        // keep DMA issue ahead of compute
    compute(Kb[0], Vb[0], El[0]);             // compute even tile
    __syncthreads();                          // drains vmcnt (covered) + barrier
    if (tt < 7) stage(tt * 2 + 2, 0);         // prefetch next even tile
    __builtin_amdgcn_sched_barrier(0);
    compute(Kb[1], Vb[1], El[1]);             // compute odd tile
    __syncthreads();
  }

  u16* obase = attn + (size_t)(b * 4096 + q0 + lr) * 512 + h * 64 + lc * 4;
  #pragma unroll
  for (int g = 0; g < 2; ++g) {
    float s = dn[g];
    s += __shfl_xor(s, 16); s += __shfl_xor(s, 32);   // sum lane's k-subsets over lc
    const float inv = 1.0f / s;
    #pragma unroll
    for (int m = 0; m < 4; ++m) {
      uint2 pw;
      pw.x = pk2(o[g][m][0] * inv, o[g][m][1] * inv);
      pw.y = pk2(o[g][m][2] * inv, o[g][m][3] * inv);
      *reinterpret_cast<uint2*>(obase + (size_t)g * 16 * 512 + m * 16) = pw;
    }
  }
}

// ---------------------------------------------------------------------------
// out = attn[16384][512] @ wo + bo -> fp32 [16384][64]
// ---------------------------------------------------------------------------
__global__ __launch_bounds__(64) void k_out(
    const u16* __restrict__ attn, const u16* __restrict__ woT,
    const float* __restrict__ bo, float* __restrict__ out) {
  const int lane = threadIdx.x, lr = lane & 15, lc = lane >> 4;
  const int np0 = blockIdx.x * 16;
  const u16* arow = attn + (size_t)(np0 + lr) * 512;
  f32x4 acc[4] = {{0.f,0.f,0.f,0.f},{0.f,0.f,0.f,0.f},{0.f,0.f,0.f,0.f},{0.f,0.f,0.f,0.f}};
  #pragma unroll
  for (int kc = 0; kc < 16; ++kc) {
    const bf16x8 bfr = asb(ldg16(arow + kc * 32 + lc * 8));
    #pragma unroll
    for (int et = 0; et < 4; ++et) {
      const bf16x8 wa = asb(ldg16(woT + (size_t)(et * 16 + lr) * 512 + kc * 32 + lc * 8));
      acc[et] = mfma16(wa, bfr, acc[et]);
    }
  }
  #pragma unroll
  for (int et = 0; et < 4; ++et) {
    const f32x4 bov = *reinterpret_cast<const f32x4*>(bo + et * 16 + lc * 4);
    const f32x4 r = acc[et] + bov;
    *reinterpret_cast<f32x4*>(out + (size_t)(np0 + lr) * 64 + et * 16 + lc * 4) = r;
  }
}

// ---------------------------------------------------------------------------
extern "C" void kernel_launch(void* const* d_in, const int* in_sizes, int n_in,
                              void* d_out, int out_size, void* d_ws, size_t ws_size,
                              hipStream_t stream) {
  (void)in_sizes; (void)n_in; (void)out_size; (void)ws_size;
  const float* vox   = (const float*)d_in[0];
  const float* desc  = (const float*)d_in[1];
  const float* cw    = (const float*)d_in[2];
  const float* cb    = (const float*)d_in[3];
  const float* lng   = (const float*)d_in[4];
  const float* lnb   = (const float*)d_in[5];
  const float* pos   = (const float*)d_in[6];
  const float* wq    = (const float*)d_in[7];
  const float* bq    = (const float*)d_in[8];
  const float* wk    = (const float*)d_in[9];
  const float* bk    = (const float*)d_in[10];
  const float* wv    = (const float*)d_in[11];
  const float* bv    = (const float*)d_in[12];
  const float* wd    = (const float*)d_in[13];
  const float* bd    = (const float*)d_in[14];
  const float* alpha = (const float*)d_in[15];
  const float* wo    = (const float*)d_in[16];
  const float* bo    = (const float*)d_in[17];
  float* out = (float*)d_out;

  char* ws = (char*)d_ws;
  size_t off = 0;
  auto alloc = [&](size_t bytes) {
    char* p = ws + off;
    off += (bytes + 255) & ~(size_t)255;
    return p;
  };
  u16*   vox_emb = (u16*)alloc((size_t)16384 * 64 * 2);
  u16*   descb   = (u16*)alloc((size_t)4096 * 256 * 2);
  u16*   desemb  = (u16*)alloc((size_t)4096 * 64 * 2);
  u16*   kb      = (u16*)alloc((size_t)4096 * 512 * 2);
  u16*   vtb     = (u16*)alloc((size_t)4096 * 512 * 2);
  float* ekl     = (float*)alloc((size_t)32768 * 4);
  u16*   attn    = (u16*)alloc((size_t)16384 * 512 * 2);
  u16*   wqT     = (u16*)alloc((size_t)32768 * 2);
  u16*   wkT     = (u16*)alloc((size_t)32768 * 2);
  u16*   wvT     = (u16*)alloc((size_t)32768 * 2);
  u16*   wdT     = (u16*)alloc((size_t)16384 * 2);
  u16*   woT     = (u16*)alloc((size_t)32768 * 2);

  k_prep<<<1600, 256, 0, stream>>>(wq, wk, wv, wd, wo, desc, wqT, wkT, wvT, wdT, woT, descb);
  k_convln<<<512, 256, 0, stream>>>(vox, cw, cb, lng, lnb, pos, vox_emb);
  k_des<<<dim3(256, 4), 64, 0, stream>>>(descb, wdT, bd, desemb);
  k_kvproj<<<dim3(256, 8), 64, 0, stream>>>(desemb, wkT, bk, wvT, bv, kb, ekl, vtb);
  k_attn<<<dim3(32, 32), 256, 0, stream>>>(vox_emb, wqT, bq, alpha, kb, ekl, vtb, attn);
  k_out<<<1024, 64, 0, stream>>>(attn, woT, bo, out);
}

// Round 11
// 96.846 us; speedup vs baseline: 1.3159x; 1.3159x over previous
//
#include <hip/hip_runtime.h>

typedef unsigned short u16;
typedef __bf16 bf16x8 __attribute__((ext_vector_type(8)));
typedef float f32x4 __attribute__((ext_vector_type(4)));

struct alignas(16) V4 { unsigned x, y, z, w; };

#if __has_builtin(__builtin_amdgcn_exp2f)
#define EXP2(x) __builtin_amdgcn_exp2f(x)
#else
#define EXP2(x) __expf((x) * 0.6931471805599453f)
#endif
#define L2E 1.4426950408889634f

// f32 -> bf16 RTNE (bit-twiddle; HW-verified R1/R4)
__device__ __forceinline__ u16 f2b(float f) {
  unsigned u = __builtin_bit_cast(unsigned, f);
  u += 0x7FFFu + ((u >> 16) & 1u);
  return (u16)(u >> 16);
}
// RTNE pack of two f32 -> u32 (lo = a, hi = b)
__device__ __forceinline__ unsigned pk2(float a, float b) {
  return (unsigned)f2b(a) | ((unsigned)f2b(b) << 16);
}
// HW packed cvt: used ONLY for P fragment (validated R8/R9/R10: absmax unchanged)
__device__ __forceinline__ unsigned pkbf(float a, float b) {
  unsigned d;
  asm("v_cvt_pk_bf16_f32 %0, %1, %2" : "=v"(d) : "v"(a), "v"(b));
  return d;
}
__device__ __forceinline__ bf16x8 asb(V4 v) { return __builtin_bit_cast(bf16x8, v); }
__device__ __forceinline__ bf16x8 mk8(unsigned a, unsigned b, unsigned c, unsigned d) {
  V4 v; v.x = a; v.y = b; v.z = c; v.w = d; return asb(v);
}
__device__ __forceinline__ V4 ldg16(const u16* p) { return *reinterpret_cast<const V4*>(p); }
__device__ __forceinline__ f32x4 mfma16(bf16x8 a, bf16x8 b, f32x4 c) {
  return __builtin_amdgcn_mfma_f32_16x16x32_bf16(a, b, c, 0, 0, 0);
}
// Direct global->LDS DMA, 16B/lane, LDS dest = wave-uniform base + lane*16.
__device__ __forceinline__ void gload_lds16(const void* g, void* l) {
  __builtin_amdgcn_global_load_lds(
      (const __attribute__((address_space(1))) int*)g,
      (__attribute__((address_space(3))) int*)l, 16, 0, 0);
}

// ---------------------------------------------------------------------------
// Prep: transpose+cast weights to bf16, cast descriptor to bf16.
// ---------------------------------------------------------------------------
__global__ __launch_bounds__(256) void k_prep(
    const float* __restrict__ wq, const float* __restrict__ wk,
    const float* __restrict__ wv, const float* __restrict__ wd,
    const float* __restrict__ wo, const float* __restrict__ desc,
    u16* __restrict__ wqT, u16* __restrict__ wkT, u16* __restrict__ wvT,
    u16* __restrict__ wdT, u16* __restrict__ woT, u16* __restrict__ descb) {
  int i = blockIdx.x * 256 + threadIdx.x;
  if (i < 32768) {                                   // wqT[n][d] = wq[d][n]
    int n = i >> 6, d = i & 63;
    wqT[i] = f2b(wq[d * 512 + n]);
  } else if (i < 65536) {
    int j = i - 32768; int n = j >> 6, d = j & 63;
    wkT[j] = f2b(wk[d * 512 + n]);
  } else if (i < 98304) {
    int j = i - 65536; int n = j >> 6, d = j & 63;
    wvT[j] = f2b(wv[d * 512 + n]);
  } else if (i < 114688) {                           // wdT[e][v] = wd[v][e]
    int j = i - 98304; int e = j >> 8, v = j & 255;
    wdT[j] = f2b(wd[v * 64 + e]);
  } else if (i < 147456) {                           // woT[n][k] = wo[k][n]
    int j = i - 114688; int n = j >> 9, kk = j & 511;
    woT[j] = f2b(wo[kk * 64 + n]);
  } else if (i < 409600) {                           // descb, 4 elems/thread
    int j = (i - 147456) * 4;
    const f32x4 dv = *reinterpret_cast<const f32x4*>(desc + j);
    uint2 pw; pw.x = pk2(dv[0], dv[1]); pw.y = pk2(dv[2], dv[3]);
    *reinterpret_cast<uint2*>(descb + j) = pw;
  }
}

// ---------------------------------------------------------------------------
// Conv3d(P=4,stride=4) + LayerNorm + pos_emb -> vox_emb bf16 [16384][64]
// ---------------------------------------------------------------------------
__global__ __launch_bounds__(256) void k_convln(
    const float* __restrict__ vox, const float* __restrict__ cw,
    const float* __restrict__ cb, const float* __restrict__ lng,
    const float* __restrict__ lnb, const float* __restrict__ pos,
    u16* __restrict__ vox_emb) {
  __shared__ float wT[64 * 65];
  __shared__ float pl[4][64];
  const int t = threadIdx.x;
  for (int i = t; i < 4096; i += 256) wT[(i & 63) * 65 + (i >> 6)] = cw[i];
  __syncthreads();
  const int w = t >> 6, lane = t & 63;
  const float cbl = cb[lane], lg = lng[lane], lb = lnb[lane];
  const int i3 = lane >> 4, j3 = (lane >> 2) & 3, k3 = lane & 3;
  for (int i = 0; i < 8; ++i) {
    const int row = blockIdx.x * 32 + w * 8 + i;
    const int b = row >> 12, np = row & 4095;
    const int pd = np >> 8, ph = (np >> 4) & 15, pw = np & 15;
    pl[w][lane] = vox[(size_t)b * 262144 + (size_t)(pd * 4 + i3) * 4096 +
                      (ph * 4 + j3) * 64 + (pw * 4 + k3)];
    float acc = cbl;
    #pragma unroll
    for (int v = 0; v < 64; ++v) acc += pl[w][v] * wT[v * 65 + lane];
    float s1 = acc, s2 = acc * acc;
    #pragma unroll
    for (int m = 1; m < 64; m <<= 1) { s1 += __shfl_xor(s1, m); s2 += __shfl_xor(s2, m); }
    const float mu = s1 * (1.0f / 64.0f);
    const float var = s2 * (1.0f / 64.0f) - mu * mu;
    const float y = (acc - mu) * rsqrtf(var + 1e-5f) * lg + lb + pos[np * 64 + lane];
    vox_emb[(size_t)row * 64 + lane] = f2b(y);
  }
}

// ---------------------------------------------------------------------------
// des_emb = descb[4096][256] @ wd + bd -> bf16 [4096][64]
// ---------------------------------------------------------------------------
__global__ __launch_bounds__(64) void k_des(
    const u16* __restrict__ descb, const u16* __restrict__ wdT,
    const float* __restrict__ bd, u16* __restrict__ desemb) {
  const int lane = threadIdx.x, lr = lane & 15, lc = lane >> 4;
  const int sd0 = blockIdx.x * 16, et = blockIdx.y;
  f32x4 acc = {0.f, 0.f, 0.f, 0.f};
  #pragma unroll
  for (int kc = 0; kc < 8; ++kc) {
    const bf16x8 db = asb(ldg16(descb + (size_t)(sd0 + lr) * 256 + kc * 32 + lc * 8));
    const bf16x8 wa = asb(ldg16(wdT + (size_t)(et * 16 + lr) * 256 + kc * 32 + lc * 8));
    acc = mfma16(wa, db, acc);
  }
  const f32x4 bdv = *reinterpret_cast<const f32x4*>(bd + et * 16 + lc * 4);
  uint2 pw;
  pw.x = pk2(acc[0] + bdv[0], acc[1] + bdv[1]);
  pw.y = pk2(acc[2] + bdv[2], acc[3] + bdv[3]);
  *reinterpret_cast<uint2*>(desemb + (size_t)(sd0 + lr) * 64 + et * 16 + lc * 4) = pw;
}

// ---------------------------------------------------------------------------
// K/V projections. Images per (bh, 64-row tile): K 8KB (row sd: 128B,
// col16 ^= sd&7), V 8KB (row e: 128B, col16 ^= e&7). ekl = -|k|^2/2 f32.
// (Layouts byte-identical to R10 — validated by exact absmax round-trip.)
// ---------------------------------------------------------------------------
__global__ __launch_bounds__(64) void k_kvproj(
    const u16* __restrict__ desemb, const u16* __restrict__ wkT,
    const float* __restrict__ bk, const u16* __restrict__ wvT,
    const float* __restrict__ bv, u16* __restrict__ kb,
    float* __restrict__ ekl, u16* __restrict__ vtb) {
  const int lane = threadIdx.x, lr = lane & 15, lc = lane >> 4;
  const int x = blockIdx.x, h = blockIdx.y;
  const int b = x >> 6, sb = x & 63, sd0 = sb * 16;
  char* kbc = reinterpret_cast<char*>(kb);
  char* vtc = reinterpret_cast<char*>(vtb);
  const u16* drow = desemb + (size_t)(x * 16 + lr) * 64;
  const bf16x8 da0 = asb(ldg16(drow + lc * 8));
  const bf16x8 da1 = asb(ldg16(drow + 32 + lc * 8));
  const int sd = sd0 + lr, ktK = sd >> 6, rK = sd & 63, xrK = sd & 7;
  float sq = 0.f;
  #pragma unroll
  for (int et = 0; et < 4; ++et) {                  // K pass (flipped)
    const int etg = h * 4 + et;
    const u16* wrow = wkT + (size_t)(etg * 16 + lr) * 64;
    f32x4 acc = {0.f, 0.f, 0.f, 0.f};
    acc = mfma16(asb(ldg16(wrow + lc * 8)), da0, acc);
    acc = mfma16(asb(ldg16(wrow + 32 + lc * 8)), da1, acc);
    const f32x4 bkv = *reinterpret_cast<const f32x4*>(bk + etg * 16 + lc * 4);
    const float k0 = acc[0] + bkv[0], k1 = acc[1] + bkv[1];
    const float k2 = acc[2] + bkv[2], k3 = acc[3] + bkv[3];
    sq += k0 * k0 + k1 * k1 + k2 * k2 + k3 * k3;
    const int col16s = (((et >> 1) * 4 + lc) ^ xrK);
    uint2 pw; pw.x = pk2(k0, k1); pw.y = pk2(k2, k3);
    *reinterpret_cast<uint2*>(kbc + (size_t)(b * 8 + h) * 131072 + ktK * 8192 +
                              rK * 128 + col16s * 16 + (et & 1) * 8) = pw;
  }
  {
    float s = sq;
    s += __shfl_xor(s, 16); s += __shfl_xor(s, 32);
    if (lc == 0) ekl[(size_t)(b * 8 + h) * 1024 + sd0 + lr] = -0.5f * s;
  }
  const int ktV = sb >> 2, kkl2 = (sb >> 1) & 1, half8 = sb & 1;
  #pragma unroll
  for (int et = 0; et < 4; ++et) {                  // V pass
    const int etg = h * 4 + et;
    const u16* wrow = wvT + (size_t)(etg * 16 + lr) * 64;
    f32x4 acc = {0.f, 0.f, 0.f, 0.f};
    acc = mfma16(da0, asb(ldg16(wrow + lc * 8)), acc);
    acc = mfma16(da1, asb(ldg16(wrow + 32 + lc * 8)), acc);
    const float bvs = bv[etg * 16 + lr];
    const int e = et * 16 + lr;
    const int col16s = ((kkl2 * 4 + lc) ^ (e & 7));
    uint2 pw;
    pw.x = pk2(acc[0] + bvs, acc[1] + bvs);
    pw.y = pk2(acc[2] + bvs, acc[3] + bvs);
    *reinterpret_cast<uint2*>(vtc + (size_t)(b * 8 + h) * 131072 + ktV * 8192 +
                              e * 128 + col16s * 16 + half8 * 8) = pw;
  }
}

// ---------------------------------------------------------------------------
// Fused Q-projection + L2 attention. Frozen arithmetic (R8/R9/R10-validated).
// R11: R10's double-buffer schedule with a SINGLE compute body (runtime
// buffer index = LDS offset, no register-array indexing, no sched_barrier)
// to avoid R10's spill. stage(tt+1) issued before compute(tt); one
// __syncthreads per tile drains an already-covered vmcnt.
// ---------------------------------------------------------------------------
__global__ __launch_bounds__(256, 4) void k_attn(
    const u16* __restrict__ vox_emb, const u16* __restrict__ wqT,
    const float* __restrict__ bq, const float* __restrict__ alpha,
    const u16* __restrict__ kb, const float* __restrict__ eklg,
    const u16* __restrict__ vtb, u16* __restrict__ attn) {
  __shared__ __align__(16) char Kb[2][8192];   // 64 rows x 128B per buffer
  __shared__ __align__(16) char Vb[2][8192];   // 64 e-rows x 128B per buffer
  __shared__ __align__(16) float El[2][64];    // -|k|^2/2 per buffer
  const int t = threadIdx.x, w = t >> 6, lane = t & 63, lr = lane & 15, lc = lane >> 4;
  const int bh = blockIdx.y, b = bh >> 3, h = bh & 7;
  const int q0 = blockIdx.x * 128 + w * 32;   // this wave's 32 q rows

  // ---- Q: q = vox_emb @ wq + bq; fragments hold f2b(q) (unscaled, frozen)
  bf16x8 qf0[2], qf1[2];
  float avL[2];
  {
    bf16x8 vb0[2], vb1[2];
    #pragma unroll
    for (int g = 0; g < 2; ++g) {
      const u16* vrow = vox_emb + (size_t)(b * 4096 + q0 + g * 16 + lr) * 64;
      vb0[g] = asb(ldg16(vrow + lc * 8));
      vb1[g] = asb(ldg16(vrow + 32 + lc * 8));
    }
    float sq[2] = {0.f, 0.f};
    unsigned qd[2][4][2];
    #pragma unroll
    for (int et = 0; et < 4; ++et) {
      const u16* wrow = wqT + (size_t)((h * 4 + et) * 16 + lr) * 64;
      const bf16x8 wa0 = asb(ldg16(wrow + lc * 8));
      const bf16x8 wa1 = asb(ldg16(wrow + 32 + lc * 8));
      const f32x4 bqv = *reinterpret_cast<const f32x4*>(bq + (h * 4 + et) * 16 + lc * 4);
      #pragma unroll
      for (int g = 0; g < 2; ++g) {
        f32x4 acc = {0.f, 0.f, 0.f, 0.f};
        acc = mfma16(wa0, vb0[g], acc);
        acc = mfma16(wa1, vb1[g], acc);
        const float v0 = acc[0] + bqv[0], v1 = acc[1] + bqv[1];
        const float v2 = acc[2] + bqv[2], v3 = acc[3] + bqv[3];
        sq[g] += v0 * v0 + v1 * v1 + v2 * v2 + v3 * v3;
        qd[g][et][0] = pk2(v0, v1);
        qd[g][et][1] = pk2(v2, v3);
      }
    }
    const float ca = L2E * 0.125f * alpha[0];
    #pragma unroll
    for (int g = 0; g < 2; ++g) {
      float s = sq[g];
      s += __shfl_xor(s, 16); s += __shfl_xor(s, 32);
      avL[g] = ca * __expf(-s);     // log2e * alpha*SCALE*exp(-|q|^2)
      qf0[g] = mk8(qd[g][0][0], qd[g][0][1], qd[g][1][0], qd[g][1][1]);
      qf1[g] = mk8(qd[g][2][0], qd[g][2][1], qd[g][3][0], qd[g][3][1]);
    }
  }

  const f32x4 z = {0.f, 0.f, 0.f, 0.f};
  f32x4 o[2][4];
  float dn[2] = {0.f, 0.f};
  #pragma unroll
  for (int g = 0; g < 2; ++g)
    #pragma unroll
    for (int m = 0; m < 4; ++m) o[g][m] = z;

  const char* kimg = reinterpret_cast<const char*>(kb) + (size_t)bh * 131072;
  const char* vimg = reinterpret_cast<const char*>(vtb) + (size_t)bh * 131072;
  const float* ekh = eklg + (size_t)bh * 1024;
  const int xr = lr & 7;
  const float C2 = 2.8853900817779268f;        // 2*log2(e)

  // prologue: stage tile 0 into buffer 0
  {
    const char* kg = kimg + w * 2048 + lane * 16;
    const char* vg = vimg + w * 2048 + lane * 16;
    gload_lds16(kg, Kb[0] + w * 2048); gload_lds16(kg + 1024, Kb[0] + w * 2048 + 1024);
    gload_lds16(vg, Vb[0] + w * 2048); gload_lds16(vg + 1024, Vb[0] + w * 2048 + 1024);
    if (w == 0 && lane < 16)
      gload_lds16(reinterpret_cast<const char*>(ekh) + lane * 16,
                  reinterpret_cast<char*>(El[0]));
  }
  __syncthreads();

  for (int tt = 0; tt < 16; ++tt) {
    const int pb = tt & 1;
    if (tt < 15) {                 // issue next tile's DMA (covered by compute)
      const int nb = pb ^ 1;
      const char* kg = kimg + (size_t)(tt + 1) * 8192 + w * 2048 + lane * 16;
      const char* vg = vimg + (size_t)(tt + 1) * 8192 + w * 2048 + lane * 16;
      gload_lds16(kg, Kb[nb] + w * 2048); gload_lds16(kg + 1024, Kb[nb] + w * 2048 + 1024);
      gload_lds16(vg, Vb[nb] + w * 2048); gload_lds16(vg + 1024, Vb[nb] + w * 2048 + 1024);
      if (w == 0 && lane < 16)
        gload_lds16(reinterpret_cast<const char*>(ekh + (tt + 1) * 64) + lane * 16,
                    reinterpret_cast<char*>(El[nb]));
    }
    // compute tile tt from buffer pb
    const char* Kt = Kb[pb];
    const char* Vt = Vb[pb];
    const float* Et = El[pb];
    #pragma unroll
    for (int c2 = 0; c2 < 2; ++c2) {
      const char* kr0 = Kt + (c2 * 32 + lr) * 128;
      const char* kr1 = kr0 + 2048;
      const bf16x8 ka00 = asb(*reinterpret_cast<const V4*>(kr0 + ((lc ^ xr) << 4)));
      const bf16x8 ka01 = asb(*reinterpret_cast<const V4*>(kr0 + (((lc + 4) ^ xr) << 4)));
      const bf16x8 ka10 = asb(*reinterpret_cast<const V4*>(kr1 + ((lc ^ xr) << 4)));
      const bf16x8 ka11 = asb(*reinterpret_cast<const V4*>(kr1 + (((lc + 4) ^ xr) << 4)));
      const int vcol = ((c2 * 4 + lc) ^ xr) << 4;
      const char* vrb = Vt + lr * 128 + vcol;
      const bf16x8 va0 = asb(*reinterpret_cast<const V4*>(vrb));
      const bf16x8 va1 = asb(*reinterpret_cast<const V4*>(vrb + 2048));
      const bf16x8 va2 = asb(*reinterpret_cast<const V4*>(vrb + 4096));
      const bf16x8 va3 = asb(*reinterpret_cast<const V4*>(vrb + 6144));
      const f32x4 ce0 = *reinterpret_cast<const f32x4*>(Et + c2 * 32 + lc * 4);
      const f32x4 ce1 = *reinterpret_cast<const f32x4*>(Et + c2 * 32 + 16 + lc * 4);
      #pragma unroll
      for (int g = 0; g < 2; ++g) {
        f32x4 s0 = ce0, s1 = ce1;   // C-init = -|k|^2/2
        s0 = mfma16(ka00, qf0[g], s0); s0 = mfma16(ka01, qf1[g], s0);
        s1 = mfma16(ka10, qf0[g], s1); s1 = mfma16(ka11, qf1[g], s1);
        const float t00 = EXP2(C2 * s0[0]), t01 = EXP2(C2 * s0[1]);
        const float t02 = EXP2(C2 * s0[2]), t03 = EXP2(C2 * s0[3]);
        const float t10 = EXP2(C2 * s1[0]), t11 = EXP2(C2 * s1[1]);
        const float t12 = EXP2(C2 * s1[2]), t13 = EXP2(C2 * s1[3]);
        const float p00 = EXP2(avL[g] * t00), p01 = EXP2(avL[g] * t01);
        const float p02 = EXP2(avL[g] * t02), p03 = EXP2(avL[g] * t03);
        const float p10 = EXP2(avL[g] * t10), p11 = EXP2(avL[g] * t11);
        const float p12 = EXP2(avL[g] * t12), p13 = EXP2(avL[g] * t13);
        dn[g] += ((p00 + p01) + (p02 + p03)) + ((p10 + p11) + (p12 + p13));
        const bf16x8 pf = mk8(pkbf(p00, p01), pkbf(p02, p03),
                              pkbf(p10, p11), pkbf(p12, p13));
        o[g][0] = mfma16(va0, pf, o[g][0]);
        o[g][1] = mfma16(va1, pf, o[g][1]);
        o[g][2] = mfma16(va2, pf, o[g][2]);
        o[g][3] = mfma16(va3, pf, o[g][3]);
      }
    }
    __syncthreads();   // drains (covered) vmcnt + protects buffers
  }

  u16* obase = attn + (size_t)(b * 4096 + q0 + lr) * 512 + h * 64 + lc * 4;
  #pragma unroll
  for (int g = 0; g < 2; ++g) {
    float s = dn[g];
    s += __shfl_xor(s, 16); s += __shfl_xor(s, 32);   // sum lane's k-subsets over lc
    const float inv = 1.0f / s;
    #pragma unroll
    for (int m = 0; m < 4; ++m) {
      uint2 pw;
      pw.x = pk2(o[g][m][0] * inv, o[g][m][1] * inv);
      pw.y = pk2(o[g][m][2] * inv, o[g][m][3] * inv);
      *reinterpret_cast<uint2*>(obase + (size_t)g * 16 * 512 + m * 16) = pw;
    }
  }
}

// ---------------------------------------------------------------------------
// out = attn[16384][512] @ wo + bo -> fp32 [16384][64]
// ---------------------------------------------------------------------------
__global__ __launch_bounds__(64) void k_out(
    const u16* __restrict__ attn, const u16* __restrict__ woT,
    const float* __restrict__ bo, float* __restrict__ out) {
  const int lane = threadIdx.x, lr = lane & 15, lc = lane >> 4;
  const int np0 = blockIdx.x * 16;
  const u16* arow = attn + (size_t)(np0 + lr) * 512;
  f32x4 acc[4] = {{0.f,0.f,0.f,0.f},{0.f,0.f,0.f,0.f},{0.f,0.f,0.f,0.f},{0.f,0.f,0.f,0.f}};
  #pragma unroll
  for (int kc = 0; kc < 16; ++kc) {
    const bf16x8 bfr = asb(ldg16(arow + kc * 32 + lc * 8));
    #pragma unroll
    for (int et = 0; et < 4; ++et) {
      const bf16x8 wa = asb(ldg16(woT + (size_t)(et * 16 + lr) * 512 + kc * 32 + lc * 8));
      acc[et] = mfma16(wa, bfr, acc[et]);
    }
  }
  #pragma unroll
  for (int et = 0; et < 4; ++et) {
    const f32x4 bov = *reinterpret_cast<const f32x4*>(bo + et * 16 + lc * 4);
    const f32x4 r = acc[et] + bov;
    *reinterpret_cast<f32x4*>(out + (size_t)(np0 + lr) * 64 + et * 16 + lc * 4) = r;
  }
}

// ---------------------------------------------------------------------------
extern "C" void kernel_launch(void* const* d_in, const int* in_sizes, int n_in,
                              void* d_out, int out_size, void* d_ws, size_t ws_size,
                              hipStream_t stream) {
  (void)in_sizes; (void)n_in; (void)out_size; (void)ws_size;
  const float* vox   = (const float*)d_in[0];
  const float* desc  = (const float*)d_in[1];
  const float* cw    = (const float*)d_in[2];
  const float* cb    = (const float*)d_in[3];
  const float* lng   = (const float*)d_in[4];
  const float* lnb   = (const float*)d_in[5];
  const float* pos   = (const float*)d_in[6];
  const float* wq    = (const float*)d_in[7];
  const float* bq    = (const float*)d_in[8];
  const float* wk    = (const float*)d_in[9];
  const float* bk    = (const float*)d_in[10];
  const float* wv    = (const float*)d_in[11];
  const float* bv    = (const float*)d_in[12];
  const float* wd    = (const float*)d_in[13];
  const float* bd    = (const float*)d_in[14];
  const float* alpha = (const float*)d_in[15];
  const float* wo    = (const float*)d_in[16];
  const float* bo    = (const float*)d_in[17];
  float* out = (float*)d_out;

  char* ws = (char*)d_ws;
  size_t off = 0;
  auto alloc = [&](size_t bytes) {
    char* p = ws + off;
    off += (bytes + 255) & ~(size_t)255;
    return p;
  };
  u16*   vox_emb = (u16*)alloc((size_t)16384 * 64 * 2);
  u16*   descb   = (u16*)alloc((size_t)4096 * 256 * 2);
  u16*   desemb  = (u16*)alloc((size_t)4096 * 64 * 2);
  u16*   kb      = (u16*)alloc((size_t)4096 * 512 * 2);
  u16*   vtb     = (u16*)alloc((size_t)4096 * 512 * 2);
  float* ekl     = (float*)alloc((size_t)32768 * 4);
  u16*   attn    = (u16*)alloc((size_t)16384 * 512 * 2);
  u16*   wqT     = (u16*)alloc((size_t)32768 * 2);
  u16*   wkT     = (u16*)alloc((size_t)32768 * 2);
  u16*   wvT     = (u16*)alloc((size_t)32768 * 2);
  u16*   wdT     = (u16*)alloc((size_t)16384 * 2);
  u16*   woT     = (u16*)alloc((size_t)32768 * 2);

  k_prep<<<1600, 256, 0, stream>>>(wq, wk, wv, wd, wo, desc, wqT, wkT, wvT, wdT, woT, descb);
  k_convln<<<512, 256, 0, stream>>>(vox, cw, cb, lng, lnb, pos, vox_emb);
  k_des<<<dim3(256, 4), 64, 0, stream>>>(descb, wdT, bd, desemb);
  k_kvproj<<<dim3(256, 8), 64, 0, stream>>>(desemb, wkT, bk, wvT, bv, kb, ekl, vtb);
  k_attn<<<dim3(32, 32), 256, 0, stream>>>(vox_emb, wqT, bq, alpha, kb, ekl, vtb, attn);
  k_out<<<1024, 64, 0, stream>>>(attn, woT, bo, out);
}